// Round 7
// baseline (310.292 us; speedup 1.0000x reference)
//
#include <hip/hip_runtime.h>
#include <hip/hip_bf16.h>

// GCN 2-layer, pull-based (CSR by dst, built on device each call).
// Round 7: gather kernels are vmem-INSTRUCTION-bound (r5->r6: bytes halved,
// time constant). Widen gathers to 16B/lane (uint4 = 8 bf16):
//   layer1: 8 lanes x 16B = one h1 row -> 8 edges per gather instr (was 4).
//   layer2: h2 stored bf16; 4 lanes x 16B = one row -> 16 edges/instr (was 8).

constexpr int SCAN_CHUNK = 1024;
constexpr unsigned long long CNT_ONE = 1ULL << 40;
constexpr unsigned long long W_MASK  = (1ULL << 40) - 1;

__device__ __forceinline__ unsigned short f2bf_rne(float f) {
    unsigned u = __float_as_uint(f);
    unsigned r = (u + 0x7FFFu + ((u >> 16) & 1u)) >> 16;
    return (unsigned short)r;
}

// accumulate 8 bf16 (packed in uint4) * s into acc[8]
__device__ __forceinline__ void bf8_fma(uint4 u, float s, float* acc) {
    acc[0] = fmaf(__uint_as_float(u.x << 16),          s, acc[0]);
    acc[1] = fmaf(__uint_as_float(u.x & 0xffff0000u),  s, acc[1]);
    acc[2] = fmaf(__uint_as_float(u.y << 16),          s, acc[2]);
    acc[3] = fmaf(__uint_as_float(u.y & 0xffff0000u),  s, acc[3]);
    acc[4] = fmaf(__uint_as_float(u.z << 16),          s, acc[4]);
    acc[5] = fmaf(__uint_as_float(u.z & 0xffff0000u),  s, acc[5]);
    acc[6] = fmaf(__uint_as_float(u.w << 16),          s, acc[6]);
    acc[7] = fmaf(__uint_as_float(u.w & 0xffff0000u),  s, acc[7]);
}

__global__ __launch_bounds__(256) void k_hist(const int* __restrict__ dst,
                                              const float* __restrict__ w,
                                              unsigned long long* __restrict__ packed,
                                              int E) {
    int e = blockIdx.x * blockDim.x + threadIdx.x;
    if (e < E) {
        unsigned long long fixw = (unsigned long long)((double)w[e] * 4294967296.0);
        atomicAdd(&packed[dst[e]], CNT_ONE | fixw);
    }
}

__global__ __launch_bounds__(256) void k_dinv(const unsigned long long* __restrict__ packed,
                                              float* __restrict__ dinv,
                                              int* __restrict__ count, int n) {
    int i = blockIdx.x * blockDim.x + threadIdx.x;
    if (i < n) {
        unsigned long long p = packed[i];
        double d = (double)(p & W_MASK) * (1.0 / 4294967296.0) + 1.0;  // +1 self loop
        dinv[i] = rsqrtf((float)d);
        count[i] = (int)(p >> 40);
    }
}

__global__ __launch_bounds__(256) void k_scan_a(const int* __restrict__ count,
                                                int* __restrict__ bsum, int n) {
    __shared__ int wtot[4];
    const int t = threadIdx.x;
    const int base = blockIdx.x * SCAN_CHUNK + t * 4;
    int s = 0;
    #pragma unroll
    for (int k = 0; k < 4; ++k) {
        int i = base + k;
        if (i < n) s += count[i];
    }
    #pragma unroll
    for (int off = 1; off < 64; off <<= 1) s += __shfl_xor(s, off, 64);
    if ((t & 63) == 0) wtot[t >> 6] = s;
    __syncthreads();
    if (t == 0) bsum[blockIdx.x] = wtot[0] + wtot[1] + wtot[2] + wtot[3];
}

__global__ __launch_bounds__(1024) void k_scan_b(int* __restrict__ bsum, int P) {
    __shared__ int wtot[16];
    const int t = threadIdx.x;
    const int lane = t & 63, wv = t >> 6;
    int v = (t < P) ? bsum[t] : 0;
    int inc = v;
    #pragma unroll
    for (int off = 1; off < 64; off <<= 1) {
        int u = __shfl_up(inc, off, 64);
        if (lane >= off) inc += u;
    }
    if (lane == 63) wtot[wv] = inc;
    __syncthreads();
    int wbase = 0;
    for (int w = 0; w < wv; ++w) wbase += wtot[w];
    if (t < P) bsum[t] = wbase + inc - v;   // exclusive
}

__global__ __launch_bounds__(256) void k_scan_c(const int* __restrict__ count,
                                                const int* __restrict__ bsum,
                                                int* __restrict__ rowst,
                                                int* __restrict__ cursor, int n) {
    __shared__ int wtot[4];
    const int t = threadIdx.x;
    const int lane = t & 63, wv = t >> 6;
    const int base = blockIdx.x * SCAN_CHUNK + t * 4;
    int c[4];
    int s = 0;
    #pragma unroll
    for (int k = 0; k < 4; ++k) {
        int i = base + k;
        c[k] = (i < n) ? count[i] : 0;
        s += c[k];
    }
    int inc = s;
    #pragma unroll
    for (int off = 1; off < 64; off <<= 1) {
        int u = __shfl_up(inc, off, 64);
        if (lane >= off) inc += u;
    }
    if (lane == 63) wtot[wv] = inc;
    __syncthreads();
    int run = bsum[blockIdx.x] + (inc - s);
    for (int w = 0; w < wv; ++w) run += wtot[w];
    #pragma unroll
    for (int k = 0; k < 4; ++k) {
        int i = base + k;
        if (i < n) { rowst[i] = run; cursor[i] = run; }
        run += c[k];
    }
}

__global__ __launch_bounds__(256) void k_fill(const int* __restrict__ src,
                                              const int* __restrict__ dst,
                                              const float* __restrict__ w,
                                              const float* __restrict__ dinv,
                                              int* __restrict__ cursor,
                                              int2* __restrict__ pack, int E) {
    int e = blockIdx.x * blockDim.x + threadIdx.x;
    if (e < E) {
        int s = src[e], d = dst[e];
        float nm = dinv[s] * w[e] * dinv[d];
        int pos = atomicAdd(&cursor[d], 1);
        pack[pos] = make_int2(s, __float_as_int(nm));
    }
}

// GEMM1: h1 = bf16(x @ W1)  (n x 128 @ 128 x 64). 64x64 tile, 4x4/thread.
__global__ __launch_bounds__(256) void k_gemm1(const float* __restrict__ x,
                                               const float* __restrict__ W,
                                               unsigned short* __restrict__ h, int n) {
    constexpr int TM = 64, BK = 16;
    __shared__ float xs[BK][TM + 4];
    __shared__ float ws[BK][64 + 4];
    const int tid = threadIdx.x;
    const int tx = tid & 15, ty = tid >> 4;
    const int r0 = blockIdx.x * TM;

    float acc[4][4] = {};
    for (int k0 = 0; k0 < 128; k0 += BK) {
        {
            int kk = tid & 15;
            int row = tid >> 4;
            #pragma unroll
            for (int p = 0; p < 4; ++p) {
                int rr = row + p * 16;
                xs[kk][rr] = (r0 + rr < n) ? x[(size_t)(r0 + rr) * 128 + k0 + kk] : 0.f;
            }
        }
        {
            int c = tid & 63;
            int kb = tid >> 6;
            #pragma unroll
            for (int p = 0; p < 4; ++p) {
                int kk = kb + p * 4;
                ws[kk][c] = W[(size_t)(k0 + kk) * 64 + c];
            }
        }
        __syncthreads();
        #pragma unroll
        for (int kk = 0; kk < BK; ++kk) {
            const float4 av = *reinterpret_cast<const float4*>(&xs[kk][ty * 4]);
            const float4 bv = *reinterpret_cast<const float4*>(&ws[kk][tx * 4]);
            const float a[4] = {av.x, av.y, av.z, av.w};
            const float b[4] = {bv.x, bv.y, bv.z, bv.w};
            #pragma unroll
            for (int i = 0; i < 4; ++i)
                #pragma unroll
                for (int j = 0; j < 4; ++j)
                    acc[i][j] = fmaf(a[i], b[j], acc[i][j]);
        }
        __syncthreads();
    }
    #pragma unroll
    for (int i = 0; i < 4; ++i) {
        int r = r0 + ty * 4 + i;
        if (r < n) {
            ushort4 o;
            o.x = f2bf_rne(acc[i][0]);
            o.y = f2bf_rne(acc[i][1]);
            o.z = f2bf_rne(acc[i][2]);
            o.w = f2bf_rne(acc[i][3]);
            *reinterpret_cast<ushort4*>(&h[(size_t)r * 64 + tx * 4]) = o;
        }
    }
}

// Fused layer1: pull-aggregate bf16 h1 + bias + relu + (64->32)@W2 -> h2 (bf16).
// Lane layout: g = lane>>3 (edge group 0..7), q = lane&7 (channels 8q..8q+7).
// One 16B gather instruction covers 8 edges; 16 edges/iter with pack prefetch.
__global__ __launch_bounds__(256) void k_layer1(const unsigned short* __restrict__ h1,
                                                const int2* __restrict__ pack,
                                                const int* __restrict__ rowst,
                                                const int* __restrict__ count,
                                                const float* __restrict__ dinv,
                                                const float* __restrict__ b1,
                                                const float* __restrict__ W2,
                                                unsigned short* __restrict__ h2, int n) {
    const int lane = threadIdx.x & 63;
    const int wid = (blockIdx.x * blockDim.x + threadIdx.x) >> 6;
    const int nwaves = (gridDim.x * blockDim.x) >> 6;
    const int g = lane >> 3;       // edge group 0..7
    const int q = lane & 7;        // channels 8q..8q+7
    const int half = lane >> 5, c = lane & 31;

    float w[32];
    #pragma unroll
    for (int m = 0; m < 32; ++m)
        w[m] = W2[(half * 32 + m) * 32 + c];
    float bb[8];
    #pragma unroll
    for (int m = 0; m < 8; ++m) bb[m] = b1[q * 8 + m];

    for (int v = wid; v < n; v += nwaves) {
        const float di = dinv[v];
        const float selfw = (g == 0) ? di * di : 0.f;
        float acc[8] = {0.f, 0.f, 0.f, 0.f, 0.f, 0.f, 0.f, 0.f};
        bf8_fma(*reinterpret_cast<const uint4*>(&h1[(size_t)v * 64 + q * 8]),
                selfw, acc);
        const int start = rowst[v], cnt = count[v];
        const int2* pk = pack + start;

        int j = 0;
        if (cnt >= 16) {
            int2 pa = pk[g];
            int2 pb = pk[8 + g];
            for (; j + 32 <= cnt; j += 16) {
                int2 na = pk[j + 16 + g];
                int2 nb = pk[j + 24 + g];
                uint4 a = *reinterpret_cast<const uint4*>(&h1[(size_t)pa.x * 64 + q * 8]);
                uint4 b = *reinterpret_cast<const uint4*>(&h1[(size_t)pb.x * 64 + q * 8]);
                bf8_fma(a, __int_as_float(pa.y), acc);
                bf8_fma(b, __int_as_float(pb.y), acc);
                pa = na; pb = nb;
            }
            {   // drain in-flight block (edges j..j+15)
                uint4 a = *reinterpret_cast<const uint4*>(&h1[(size_t)pa.x * 64 + q * 8]);
                uint4 b = *reinterpret_cast<const uint4*>(&h1[(size_t)pb.x * 64 + q * 8]);
                bf8_fma(a, __int_as_float(pa.y), acc);
                bf8_fma(b, __int_as_float(pb.y), acc);
                j += 16;
            }
        }
        for (; j < cnt; j += 8) {   // predicated tail, <=2 iters
            int e = j + g;
            int2 p = (e < cnt) ? pk[e] : make_int2(v, 0);
            uint4 a = *reinterpret_cast<const uint4*>(&h1[(size_t)p.x * 64 + q * 8]);
            bf8_fma(a, __int_as_float(p.y), acc);
        }

        // reduce across the 8 edge groups (lane bits 3,4,5)
        #pragma unroll
        for (int m = 0; m < 8; ++m) {
            acc[m] += __shfl_xor(acc[m], 8, 64);
            acc[m] += __shfl_xor(acc[m], 16, 64);
            acc[m] += __shfl_xor(acc[m], 32, 64);
        }

        // bias + relu (leaky_relu = identity on >=0); lanes 0..7 hold the row
        float r[8];
        #pragma unroll
        for (int m = 0; m < 8; ++m) r[m] = fmaxf(acc[m] + bb[m], 0.f);

        // 64->32 projection: channel k=32*half+m lives in lane 4*half+(m>>3), elem m&7
        float o = 0.f;
        #pragma unroll
        for (int m = 0; m < 32; ++m) {
            float rv = __shfl(r[m & 7], half * 4 + (m >> 3), 64);
            o = fmaf(rv, w[m], o);
        }
        o += __shfl_xor(o, 32, 64);
        if (half == 0) h2[(size_t)v * 32 + c] = f2bf_rne(o);
    }
}

// Layer2 pull from bf16 h2: out = pull(h2) + self + b2 (fp32 out).
// Lane layout: g = lane>>2 (16 edge groups), q = lane&3 (channels 8q..8q+7).
// One 16B gather instruction covers 16 edges.
__global__ __launch_bounds__(256) void k_layer2(const unsigned short* __restrict__ h2,
                                                const int2* __restrict__ pack,
                                                const int* __restrict__ rowst,
                                                const int* __restrict__ count,
                                                const float* __restrict__ dinv,
                                                const float* __restrict__ b2,
                                                float* __restrict__ out, int n) {
    const int lane = threadIdx.x & 63;
    const int wid = (blockIdx.x * blockDim.x + threadIdx.x) >> 6;
    const int nwaves = (gridDim.x * blockDim.x) >> 6;
    const int g = lane >> 2;      // edge group 0..15
    const int q = lane & 3;       // channels 8q..8q+7
    float bb[8];
    #pragma unroll
    for (int m = 0; m < 8; ++m) bb[m] = b2[q * 8 + m];

    for (int v = wid; v < n; v += nwaves) {
        const float di = dinv[v];
        const float selfw = (g == 0) ? di * di : 0.f;
        float acc[8] = {0.f, 0.f, 0.f, 0.f, 0.f, 0.f, 0.f, 0.f};
        bf8_fma(*reinterpret_cast<const uint4*>(&h2[(size_t)v * 32 + q * 8]),
                selfw, acc);
        const int start = rowst[v], cnt = count[v];
        const int2* pk = pack + start;

        int j = 0;
        if (cnt >= 16) {
            int2 pa = pk[g];
            for (; j + 32 <= cnt; j += 16) {
                int2 na = pk[j + 16 + g];
                uint4 a = *reinterpret_cast<const uint4*>(&h2[(size_t)pa.x * 32 + q * 8]);
                bf8_fma(a, __int_as_float(pa.y), acc);
                pa = na;
            }
            {   // drain (edges j..j+15)
                uint4 a = *reinterpret_cast<const uint4*>(&h2[(size_t)pa.x * 32 + q * 8]);
                bf8_fma(a, __int_as_float(pa.y), acc);
                j += 16;
            }
        }
        for (; j < cnt; j += 16) {  // predicated tail, 1 iter
            int e = j + g;
            int2 p = (e < cnt) ? pk[e] : make_int2(v, 0);
            uint4 a = *reinterpret_cast<const uint4*>(&h2[(size_t)p.x * 32 + q * 8]);
            bf8_fma(a, __int_as_float(p.y), acc);
        }

        // reduce across 16 edge groups (lane bits 2,3,4,5)
        #pragma unroll
        for (int m = 0; m < 8; ++m) {
            acc[m] += __shfl_xor(acc[m], 4, 64);
            acc[m] += __shfl_xor(acc[m], 8, 64);
            acc[m] += __shfl_xor(acc[m], 16, 64);
            acc[m] += __shfl_xor(acc[m], 32, 64);
        }

        if (g == 0) {   // lanes 0..3 hold channels 8q..8q+7
            float4 o0 = make_float4(acc[0] + bb[0], acc[1] + bb[1],
                                    acc[2] + bb[2], acc[3] + bb[3]);
            float4 o1 = make_float4(acc[4] + bb[4], acc[5] + bb[5],
                                    acc[6] + bb[6], acc[7] + bb[7]);
            *reinterpret_cast<float4*>(&out[(size_t)v * 32 + q * 8]) = o0;
            *reinterpret_cast<float4*>(&out[(size_t)v * 32 + q * 8 + 4]) = o1;
        }
    }
}

extern "C" void kernel_launch(void* const* d_in, const int* in_sizes, int n_in,
                              void* d_out, int out_size, void* d_ws, size_t ws_size,
                              hipStream_t stream) {
    const float* x  = (const float*)d_in[0];   // [n,128]
    const int*   ei = (const int*)d_in[1];     // [2,E]
    const float* ew = (const float*)d_in[2];   // [E]
    const float* W1 = (const float*)d_in[3];   // [128,64]
    const float* b1 = (const float*)d_in[4];   // [64]
    const float* W2 = (const float*)d_in[5];   // [64,32]
    const float* b2 = (const float*)d_in[6];   // [32]
    float* out = (float*)d_out;

    const int n = in_sizes[0] / 128;
    const int E = in_sizes[2];
    const int* src = ei;
    const int* dst = ei + E;

    const int P = (n + SCAN_CHUNK - 1) / SCAN_CHUNK;

    // workspace: packed u64[n] | dinv f32[n] | count[n] | rowst[n] | cursor[n] |
    //            bsum[1024] | pack[E]int2 | h1 bf16[n*64] | h2 bf16[n*32]
    unsigned long long* packed = (unsigned long long*)d_ws;
    float* dinv   = (float*)(packed + n);
    int*   count  = (int*)(dinv + n);
    int*   rowst  = count + n;
    int*   cursor = rowst + n;
    int*   bsum   = cursor + n;
    int2*  pack   = (int2*)(bsum + 1024);
    unsigned short* h1 = (unsigned short*)(pack + E);
    unsigned short* h2 = h1 + (size_t)n * 64;

    hipMemsetAsync(packed, 0, (size_t)n * sizeof(unsigned long long), stream);
    k_hist<<<(E + 255) / 256, 256, 0, stream>>>(dst, ew, packed, E);
    k_dinv<<<(n + 255) / 256, 256, 0, stream>>>(packed, dinv, count, n);
    k_scan_a<<<P, 256, 0, stream>>>(count, bsum, n);
    k_scan_b<<<1, 1024, 0, stream>>>(bsum, P);
    k_scan_c<<<P, 256, 0, stream>>>(count, bsum, rowst, cursor, n);
    k_fill<<<(E + 255) / 256, 256, 0, stream>>>(src, dst, ew, dinv, cursor, pack, E);

    k_gemm1<<<(n + 63) / 64, 256, 0, stream>>>(x, W1, h1, n);
    k_layer1<<<2048, 256, 0, stream>>>(h1, pack, rowst, count, dinv, b1, W2, h2, n);
    k_layer2<<<2048, 256, 0, stream>>>(h2, pack, rowst, count, dinv, b2, out, n);
}